// Round 8
// baseline (6399.509 us; speedup 1.0000x reference)
//
#include <hip/hip_runtime.h>

typedef __attribute__((ext_vector_type(8))) short bf16x8;
typedef __attribute__((ext_vector_type(4))) float f32x4;
typedef __attribute__((ext_vector_type(4))) unsigned u32x4;

#define MFMA16(a,b,c) __builtin_amdgcn_mfma_f32_16x16x32_bf16((a),(b),(c),0,0,0)

// ---------------- sizes ----------------
// B=256 T=512 D=32 H=256 4H=1024
// h state: one dword per unit = [hi bf16 | (lo bf16 & ~3) | 2-bit tag]

// ---------------- ws layout (bytes) ----------------
#define OFF_H0    0                        // u32 [2 parity][256 b][256 u] = 524288
#define OFF_H1    (OFF_H0 + 524288)
#define OFF_CFIN  (OFF_H1 + 524288)        // f32 [2 layer][256][256] = 524288
#define OFF_EW0H  (OFF_CFIN + 524288)      // enc L0 cat [1024][288] bf16
#define OFF_EW0L  (OFF_EW0H + 589824)
#define OFF_EW1H  (OFF_EW0L + 589824)      // enc L1 cat [1024][512] bf16
#define OFF_EW1L  (OFF_EW1H + 1048576)
#define OFF_DW0H  (OFF_EW1L + 1048576)     // dec L0 cat [Weff|Whh0] [1024][512]
#define OFF_DW0L  (OFF_DW0H + 1048576)
#define OFF_DW1H  (OFF_DW0L + 1048576)     // dec L1 cat [Wih1|Whh1]
#define OFF_DW1L  (OFF_DW1H + 1048576)
#define OFF_BEFF  (OFF_DW1L + 1048576)     // 1024 f32
#define OFF_FCWH  (OFF_BEFF + 4096)        // fc W [32][256] bf16 hi
#define OFF_FCWL  (OFF_FCWH + 16384)

// ---------------- helpers ----------------
static __device__ __forceinline__ unsigned short f2bf(float f) {
  unsigned u = __float_as_uint(f);
  u = u + 0x7fffu + ((u >> 16) & 1u);
  return (unsigned short)(u >> 16);
}
static __device__ __forceinline__ float bf2f(unsigned short s) {
  return __uint_as_float(((unsigned)s) << 16);
}
static __device__ __forceinline__ float sigf(float x) {
  return 1.f / (1.f + __expf(-x));
}
static __device__ __forceinline__ float tanhsafe(float x) {
  float a = fabsf(x);
  float e = __expf(-2.f * a);
  float t = (1.f - e) / (1.f + e);
  return x < 0.f ? -t : t;
}
// writer: pack h into tagged dword, agent-scope store (proven path)
static __device__ __forceinline__ void st_htag(unsigned* dst, float h, unsigned tag) {
  unsigned short hi = f2bf(h);
  unsigned short lo = f2bf(h - bf2f(hi));
  unsigned w = ((unsigned)hi << 16) | ((unsigned)lo & 0xFFFCu) | tag;
  __hip_atomic_store(dst, w, __ATOMIC_RELAXED, __HIP_MEMORY_SCOPE_AGENT);
}
// pipelined coherent 16B load: issue-only (valid after wait_vm0) — proven sc0 sc1
static __device__ __forceinline__ u32x4 ld16u(const void* p) {
  u32x4 d;
  asm volatile("global_load_dwordx4 %0, %1, off sc0 sc1" : "=&v"(d) : "v"(p) : "memory");
  return d;
}
static __device__ __forceinline__ f32x4 ld16(const void* p) {
  f32x4 d;
  asm volatile("global_load_dwordx4 %0, %1, off sc0 sc1" : "=&v"(d) : "v"(p) : "memory");
  return d;
}
static __device__ __forceinline__ void wait_vm0() {
  asm volatile("s_waitcnt vmcnt(0)" ::: "memory");
  __builtin_amdgcn_sched_barrier(0);
}
static __device__ __forceinline__ int tagok(u32x4 c, unsigned tag) {
  return ((c[0] & 3u) == tag) & ((c[1] & 3u) == tag) & ((c[2] & 3u) == tag) & ((c[3] & 3u) == tag);
}
// staging: thread t covers row=t>>4 (of group's 16), units (t&15)*16..+15 -> 4 chunks
static __device__ __forceinline__ void stg_issue(u32x4* c, const unsigned* p) {
  c[0] = ld16u(p); c[1] = ld16u(p + 4); c[2] = ld16u(p + 8); c[3] = ld16u(p + 12);
}
// assumes wait_vm0 already executed for the initial issue
static __device__ __forceinline__ void stg_validate(u32x4* c, const unsigned* p, unsigned tag) {
  for (;;) {
    int o0 = tagok(c[0], tag), o1 = tagok(c[1], tag), o2 = tagok(c[2], tag), o3 = tagok(c[3], tag);
    if (o0 & o1 & o2 & o3) break;
    if (!o0) c[0] = ld16u(p);
    if (!o1) c[1] = ld16u(p + 4);
    if (!o2) c[2] = ld16u(p + 8);
    if (!o3) c[3] = ld16u(p + 12);
    wait_vm0();
  }
}
static __device__ __forceinline__ void stg_validate2(u32x4* a, const unsigned* pa, unsigned ta,
                                                     u32x4* b, const unsigned* pb, unsigned tb) {
  for (;;) {
    int a0 = tagok(a[0], ta), a1 = tagok(a[1], ta), a2 = tagok(a[2], ta), a3 = tagok(a[3], ta);
    int b0 = tagok(b[0], tb), b1 = tagok(b[1], tb), b2 = tagok(b[2], tb), b3 = tagok(b[3], tb);
    if (a0 & a1 & a2 & a3 & b0 & b1 & b2 & b3) break;
    if (!a0) a[0] = ld16u(pa);     if (!a1) a[1] = ld16u(pa + 4);
    if (!a2) a[2] = ld16u(pa + 8); if (!a3) a[3] = ld16u(pa + 12);
    if (!b0) b[0] = ld16u(pb);     if (!b1) b[1] = ld16u(pb + 4);
    if (!b2) b[2] = ld16u(pb + 8); if (!b3) b[3] = ld16u(pb + 12);
    wait_vm0();
  }
}
static __device__ __forceinline__ unsigned hp2(unsigned a, unsigned b) { return (a >> 16) | (b & 0xFFFF0000u); }
static __device__ __forceinline__ unsigned lp2(unsigned a, unsigned b) { return (a & 0xFFFFu) | (b << 16); }
// unpack 16 tagged dwords -> hi/lo bf16 LDS planes (layout matches LDSF)
static __device__ __forceinline__ void stg_unpack(const u32x4* c, char* ldsH, char* ldsL, int row, int ucol) {
  u32x4 hA, hB, lA, lB;
  hA[0] = hp2(c[0][0], c[0][1]); hA[1] = hp2(c[0][2], c[0][3]);
  hA[2] = hp2(c[1][0], c[1][1]); hA[3] = hp2(c[1][2], c[1][3]);
  hB[0] = hp2(c[2][0], c[2][1]); hB[1] = hp2(c[2][2], c[2][3]);
  hB[2] = hp2(c[3][0], c[3][1]); hB[3] = hp2(c[3][2], c[3][3]);
  lA[0] = lp2(c[0][0], c[0][1]); lA[1] = lp2(c[0][2], c[0][3]);
  lA[2] = lp2(c[1][0], c[1][1]); lA[3] = lp2(c[1][2], c[1][3]);
  lB[0] = lp2(c[2][0], c[2][1]); lB[1] = lp2(c[2][2], c[2][3]);
  lB[2] = lp2(c[3][0], c[3][1]); lB[3] = lp2(c[3][2], c[3][3]);
  int sw = (row & 7) << 4;
  int a0 = ((row << 9) | (ucol << 5)) ^ sw;
  int a1 = ((row << 9) | (ucol << 5) | 16) ^ sw;
  *(u32x4*)(ldsH + a0) = hA; *(u32x4*)(ldsH + a1) = hB;
  *(u32x4*)(ldsL + a0) = lA; *(u32x4*)(ldsL + a1) = lB;
}

// swizzled LDS fragment read: 16B at (row*512 | lrow*16 | kk*64) ^ ((row&7)<<4)
#define LDSF(base, row, kk) \
  (*(const bf16x8*)((base) + ((((row) << 9) | (lrow << 4) | ((kk) << 6)) ^ (((row) & 7) << 4))))

// ---------------- prep kernels ----------------
__global__ void k_prep_cat(int nrows, const float* __restrict__ s0, int K0,
                           const float* __restrict__ s1, int K1,
                           unsigned short* __restrict__ whi, unsigned short* __restrict__ wlo) {
  int K = K0 + K1;
  int tot = nrows * K;
  for (int idx = blockIdx.x * blockDim.x + threadIdx.x; idx < tot; idx += gridDim.x * blockDim.x) {
    int n = idx / K, k = idx - n * K;
    float v = (k < K0) ? s0[n * K0 + k] : s1[n * K1 + (k - K0)];
    unsigned short hi = f2bf(v);
    unsigned short lo = f2bf(v - bf2f(hi));
    whi[idx] = hi; wlo[idx] = lo;
  }
}
__global__ void k_prep_dec0(const float* __restrict__ Wih0, const float* __restrict__ Whh0,
                            const float* __restrict__ fcW,
                            unsigned short* __restrict__ whi, unsigned short* __restrict__ wlo) {
  int tot = 1024 * 512;
  for (int idx = blockIdx.x * blockDim.x + threadIdx.x; idx < tot; idx += gridDim.x * blockDim.x) {
    int n = idx >> 9, k = idx & 511;
    float v;
    if (k < 256) {
      v = 0.f;
      #pragma unroll
      for (int d = 0; d < 32; ++d) v += Wih0[n * 32 + d] * fcW[d * 256 + k];
    } else {
      v = Whh0[n * 256 + (k - 256)];
    }
    unsigned short hi = f2bf(v);
    unsigned short lo = f2bf(v - bf2f(hi));
    whi[idx] = hi; wlo[idx] = lo;
  }
}
__global__ void k_prep_beff(const float* __restrict__ Wih0, const float* __restrict__ b0,
                            const float* __restrict__ fcb, float* __restrict__ beff) {
  int n = blockIdx.x * blockDim.x + threadIdx.x;
  if (n < 1024) {
    float v = b0[n];
    #pragma unroll
    for (int d = 0; d < 32; ++d) v += Wih0[n * 32 + d] * fcb[d];
    beff[n] = v;
  }
}

// ---------------- encoder ----------------
// R4 mapping (wave=gate, gA/gB LDS exchange), c in registers, tag-validated staging, NO barrier.
// Tags: h0 round k -> 1+(k%3); h1 step j -> 1+(j%3); initial zeros -> tag 0.
__global__ __launch_bounds__(256, 1)
void k_encoder(const float* __restrict__ input,
               const unsigned short* __restrict__ w0hi, const unsigned short* __restrict__ w0lo,
               const unsigned short* __restrict__ w1hi, const unsigned short* __restrict__ w1lo,
               const float* __restrict__ b0, const float* __restrict__ b1,
               unsigned* h0, unsigned* h1, float* __restrict__ cfin)
{
  const int wg = blockIdx.x;
  const int gb = wg & 15, gc = wg >> 4;
  const int tid = threadIdx.x;
  const int wid = tid >> 6, lane = tid & 63;
  const int lcol = lane & 15, lrow = lane >> 4;
  const int r0 = gb * 16, u0 = gc * 16;
  const int wrow = wid * 256 + u0 + lcol;
  const int row = tid >> 4, ucol = tid & 15;         // staging coords
  const int urow = tid >> 4, uu = tid & 15;          // gate coords

  __shared__ char s_h0[2][8192];   // [hi/lo] h0(k-1)
  __shared__ char s_h1[2][8192];   // [hi/lo] h1(k-2)
  __shared__ float gA[4][16][17];
  __shared__ float gB[4][16][17];

  // weights resident in VGPRs (bf16 hi+lo)
  bf16x8 w0h_[9], w0l_[9], w1h_[16], w1l_[16];
  {
    const unsigned short* p = w0hi + (size_t)wrow * 288 + lrow * 8;
    const unsigned short* q = w0lo + (size_t)wrow * 288 + lrow * 8;
    #pragma unroll
    for (int kk = 0; kk < 9; ++kk) {
      w0h_[kk] = *(const bf16x8*)(p + kk * 32);
      w0l_[kk] = *(const bf16x8*)(q + kk * 32);
    }
    const unsigned short* p1 = w1hi + (size_t)wrow * 512 + lrow * 8;
    const unsigned short* q1 = w1lo + (size_t)wrow * 512 + lrow * 8;
    #pragma unroll
    for (int kk = 0; kk < 16; ++kk) {
      w1h_[kk] = *(const bf16x8*)(p1 + kk * 32);
      w1l_[kk] = *(const bf16x8*)(q1 + kk * 32);
    }
  }
  const float bias0 = b0[wrow];
  const float bias1 = b1[wrow];
  float c0reg = 0.f, c1reg = 0.f;

  // x prologue: load+convert x(0)
  const float* pxrow = input + (size_t)(r0 + lcol) * 16384 + lrow * 8;  // + k*32
  union { bf16x8 v; unsigned short s[8]; } xh, xl;
  {
    f32x4 a = *(const f32x4*)(pxrow);
    f32x4 b = *(const f32x4*)(pxrow + 4);
    #pragma unroll
    for (int j = 0; j < 4; ++j) {
      unsigned short t1 = f2bf(a[j]); xh.s[j] = t1;     xl.s[j]     = f2bf(a[j] - bf2f(t1));
      unsigned short t2 = f2bf(b[j]); xh.s[4 + j] = t2; xl.s[4 + j] = f2bf(b[j] - bf2f(t2));
    }
  }
  const unsigned* g0base = h0 + (size_t)(r0 + row) * 256 + ucol * 16;
  const unsigned* g1base = h1 + (size_t)(r0 + row) * 256 + ucol * 16;
  unsigned* s0base = h0 + (size_t)(r0 + urow) * 256 + (u0 + uu);
  unsigned* s1base = h1 + (size_t)(r0 + urow) * 256 + (u0 + uu);
  __syncthreads();

  for (int k = 0; k <= 512; ++k) {
    const int rp = (k - 1) & 1;   // h0 read parity; h1 write parity
    const int wp = k & 1;         // h0 write parity; h1 read parity
    const unsigned e0 = (k == 0) ? 0u : (unsigned)(1 + ((k - 1) % 3));
    const unsigned e1 = (k < 2) ? 0u : (unsigned)(1 + ((k - 2) % 3));

    // issue staging loads (h0(k-1)@rp, h1(k-2)@wp) + x(k+1)
    const unsigned* p0 = g0base + (size_t)rp * 65536;
    const unsigned* p1 = g1base + (size_t)wp * 65536;
    u32x4 c0[4], c1[4];
    stg_issue(c0, p0);
    stg_issue(c1, p1);
    f32x4 nxa, nxb;
    if (k < 511) {
      nxa = ld16(pxrow + (size_t)(k + 1) * 32);
      nxb = ld16(pxrow + (size_t)(k + 1) * 32 + 4);
    }

    f32x4 ahh = {0.f,0.f,0.f,0.f}, ahl = {0.f,0.f,0.f,0.f}, alh = {0.f,0.f,0.f,0.f};
    if (k < 512) {   // overlap: x(k) MFMAs under the load shadow
      ahh = MFMA16(xh.v, w0h_[0], ahh);
      ahl = MFMA16(xh.v, w0l_[0], ahl);
      alh = MFMA16(xl.v, w0h_[0], alh);
    }

    wait_vm0();
    stg_validate2(c0, p0, e0, c1, p1, e1);
    stg_unpack(c0, s_h0[0], s_h0[1], row, ucol);
    stg_unpack(c1, s_h1[0], s_h1[1], row, ucol);
    if (k < 511) {   // convert x(k+1) for next round
      #pragma unroll
      for (int j = 0; j < 4; ++j) {
        unsigned short t1 = f2bf(nxa[j]); xh.s[j] = t1;     xl.s[j]     = f2bf(nxa[j] - bf2f(t1));
        unsigned short t2 = f2bf(nxb[j]); xh.s[4 + j] = t2; xl.s[4 + j] = f2bf(nxb[j] - bf2f(t2));
      }
    }
    __syncthreads();

    // h0(k-1) fragments feed BOTH L0 (recurrent) and L1 (sequence input)
    bf16x8 f0h[8], f0l[8];
    #pragma unroll
    for (int kk = 0; kk < 8; ++kk) {
      f0h[kk] = LDSF(s_h0[0], lcol, kk);
      f0l[kk] = LDSF(s_h0[1], lcol, kk);
    }

    if (k < 512) {  // ---- layer0 step k
      #pragma unroll
      for (int kk = 0; kk < 8; ++kk) {
        ahh = MFMA16(f0h[kk], w0h_[kk + 1], ahh);
        ahl = MFMA16(f0h[kk], w0l_[kk + 1], ahl);
        alh = MFMA16(f0l[kk], w0h_[kk + 1], alh);
      }
      f32x4 g = ahh + ahl + alh;
      #pragma unroll
      for (int r = 0; r < 4; ++r) gA[wid][lrow * 4 + r][lcol] = g[r] + bias0;
    }
    if (k >= 1) {   // ---- layer1 step k-1 : A = [h0(k-1) | h1(k-2)]
      f32x4 bhh = {0.f,0.f,0.f,0.f}, bhl = {0.f,0.f,0.f,0.f}, blh = {0.f,0.f,0.f,0.f};
      #pragma unroll
      for (int kk = 0; kk < 8; ++kk) {
        bhh = MFMA16(f0h[kk], w1h_[kk], bhh);
        bhl = MFMA16(f0h[kk], w1l_[kk], bhl);
        blh = MFMA16(f0l[kk], w1h_[kk], blh);
      }
      #pragma unroll
      for (int kk = 0; kk < 8; ++kk) {
        bf16x8 fh_ = LDSF(s_h1[0], lcol, kk);
        bf16x8 fl_ = LDSF(s_h1[1], lcol, kk);
        bhh = MFMA16(fh_, w1h_[kk + 8], bhh);
        bhl = MFMA16(fh_, w1l_[kk + 8], bhl);
        blh = MFMA16(fl_, w1h_[kk + 8], blh);
      }
      f32x4 g = bhh + bhl + blh;
      #pragma unroll
      for (int r = 0; r < 4; ++r) gB[wid][lrow * 4 + r][lcol] = g[r] + bias1;
    }
    __syncthreads();

    if (k < 512) {
      float gi = gA[0][urow][uu], gf = gA[1][urow][uu];
      float gg = gA[2][urow][uu], go = gA[3][urow][uu];
      float c = sigf(gf) * c0reg + sigf(gi) * tanhsafe(gg);
      c0reg = c;
      float h = sigf(go) * tanhsafe(c);
      st_htag(s0base + (size_t)wp * 65536, h, (unsigned)(1 + (k % 3)));
    }
    if (k >= 1) {
      float gi = gB[0][urow][uu], gf = gB[1][urow][uu];
      float gg = gB[2][urow][uu], go = gB[3][urow][uu];
      float c = sigf(gf) * c1reg + sigf(gi) * tanhsafe(gg);
      c1reg = c;
      float h = sigf(go) * tanhsafe(c);
      st_htag(s1base + (size_t)rp * 65536, h, (unsigned)(1 + ((k - 1) % 3)));
    }
    // no barrier — readers validate tags
  }

  cfin[(size_t)(r0 + urow) * 256 + (u0 + uu)] = c0reg;
  cfin[65536 + (size_t)(r0 + urow) * 256 + (u0 + uu)] = c1reg;
}

// ---------------- decoder ----------------
// Tags: h0 step t -> 1+((t+1)%3); h1 step t -> 1+((t+2)%3)   (offsets avoid encoder residuals).
__global__ __launch_bounds__(256, 1)
void k_decoder(const unsigned short* __restrict__ w0hi, const unsigned short* __restrict__ w0lo,
               const unsigned short* __restrict__ w1hi, const unsigned short* __restrict__ w1lo,
               const float* __restrict__ beff, const float* __restrict__ db0,
               const float* __restrict__ b1, const float* __restrict__ fcb,
               const unsigned short* __restrict__ fcwh_g, const unsigned short* __restrict__ fcwl_g,
               unsigned* h0, unsigned* h1,
               const float* __restrict__ cfin, float* __restrict__ out)
{
  const int wg = blockIdx.x;
  const int gb = wg & 15, gc = wg >> 4;
  const int tid = threadIdx.x;
  const int wid = tid >> 6, lane = tid & 63;
  const int lcol = lane & 15, lrow = lane >> 4;
  const int r0 = gb * 16, u0 = gc * 16;
  const int wrow = wid * 256 + u0 + lcol;
  const int row = tid >> 4, ucol = tid & 15;
  const int urow = tid >> 4, uu = tid & 15;

  __shared__ char s_h1[2][8192];        // [hi/lo] h1(t-1)
  __shared__ char s_h0[2][2][8192];     // [parity][hi/lo]
  __shared__ char s_fcw[2][16384];      // [hi/lo] fcW
  __shared__ float gA[4][16][17];

  float c0reg = cfin[(size_t)(r0 + urow) * 256 + (u0 + uu)];
  float c1reg = cfin[65536 + (size_t)(r0 + urow) * 256 + (u0 + uu)];

  const unsigned* g0base = h0 + (size_t)(r0 + row) * 256 + ucol * 16;
  const unsigned* g1base = h1 + (size_t)(r0 + row) * 256 + ucol * 16;
  unsigned* s0base = h0 + (size_t)(r0 + urow) * 256 + (u0 + uu);
  unsigned* s1base = h1 + (size_t)(r0 + urow) * 256 + (u0 + uu);

  // prologue: stage h1(final)@par1, h0(final)@par1 (kernel-boundary sync, no tags) + fcW
  {
    const int srow = (tid >> 5) & 7;
    const int scol8 = (tid & 31) << 3;
    const int dA = ((srow << 9) | ((tid & 31) << 4)) ^ (srow << 4);
    u32x4 ch1[4], ch0[4];
    stg_issue(ch1, g1base + 65536);
    stg_issue(ch0, g0base + 65536);
    f32x4 fh0 = ld16(fcwh_g + (size_t)srow * 256 + scol8);
    f32x4 fh1 = ld16(fcwh_g + (size_t)(srow + 8) * 256 + scol8);
    f32x4 fh2 = ld16(fcwh_g + (size_t)(srow + 16) * 256 + scol8);
    f32x4 fh3 = ld16(fcwh_g + (size_t)(srow + 24) * 256 + scol8);
    f32x4 fl0 = ld16(fcwl_g + (size_t)srow * 256 + scol8);
    f32x4 fl1 = ld16(fcwl_g + (size_t)(srow + 8) * 256 + scol8);
    f32x4 fl2 = ld16(fcwl_g + (size_t)(srow + 16) * 256 + scol8);
    f32x4 fl3 = ld16(fcwl_g + (size_t)(srow + 24) * 256 + scol8);
    wait_vm0();
    stg_unpack(ch1, s_h1[0], s_h1[1], row, ucol);
    stg_unpack(ch0, s_h0[1][0], s_h0[1][1], row, ucol);
    *(f32x4*)(s_fcw[0] + dA) = fh0;          *(f32x4*)(s_fcw[0] + dA + 4096) = fh1;
    *(f32x4*)(s_fcw[0] + dA + 8192) = fh2;   *(f32x4*)(s_fcw[0] + dA + 12288) = fh3;
    *(f32x4*)(s_fcw[1] + dA) = fl0;          *(f32x4*)(s_fcw[1] + dA + 4096) = fl1;
    *(f32x4*)(s_fcw[1] + dA + 8192) = fl2;   *(f32x4*)(s_fcw[1] + dA + 12288) = fl3;
  }

  // weights resident in VGPRs
  bf16x8 w0h_[16], w0l_[16], w1h_[16], w1l_[16];
  {
    const unsigned short* p = w0hi + (size_t)wrow * 512 + lrow * 8;
    const unsigned short* q = w0lo + (size_t)wrow * 512 + lrow * 8;
    #pragma unroll
    for (int kk = 0; kk < 16; ++kk) {
      w0h_[kk] = *(const bf16x8*)(p + kk * 32);
      w0l_[kk] = *(const bf16x8*)(q + kk * 32);
    }
    const unsigned short* p1 = w1hi + (size_t)wrow * 512 + lrow * 8;
    const unsigned short* q1 = w1lo + (size_t)wrow * 512 + lrow * 8;
    #pragma unroll
    for (int kk = 0; kk < 16; ++kk) {
      w1h_[kk] = *(const bf16x8*)(p1 + kk * 32);
      w1l_[kk] = *(const bf16x8*)(q1 + kk * 32);
    }
  }
  const float bias0 = beff[wrow], bias0t0 = db0[wrow], bias1 = b1[wrow];
  const float fcbv = (wid < 2) ? fcb[wid * 16 + lcol] : 0.f;
  __syncthreads();

  bf16x8 h1h_r[8], h1l_r[8];

  for (int t = 0; t < 512; ++t) {
    const int wp = t & 1, rp = 1 - wp;
    const unsigned tag0 = (unsigned)(1 + ((t + 1) % 3));   // h0(t)
    const unsigned tag1 = (unsigned)(1 + ((t + 2) % 3));   // h1(t)
    const unsigned tag1p = (unsigned)(1 + ((t + 1) % 3));  // h1(t-1)

    // ================= phase A : layer0 =================
    u32x4 ch[4];
    const unsigned* pA = g1base + (size_t)rp * 65536;
    if (t > 0) stg_issue(ch, pA);   // h1(t-1)
    // overlap: Whh0 half on s_h0[rp] (staged in phase B of t-1 / prologue)
    f32x4 ahh = {0.f,0.f,0.f,0.f}, ahl = {0.f,0.f,0.f,0.f}, alh = {0.f,0.f,0.f,0.f};
    #pragma unroll
    for (int kk = 0; kk < 8; ++kk) {
      bf16x8 fh_ = LDSF(s_h0[rp][0], lcol, kk);
      bf16x8 fl_ = LDSF(s_h0[rp][1], lcol, kk);
      ahh = MFMA16(fh_, w0h_[kk + 8], ahh);
      ahl = MFMA16(fh_, w0l_[kk + 8], ahl);
      alh = MFMA16(fl_, w0h_[kk + 8], alh);
    }
    if (t > 0) {
      wait_vm0();
      stg_validate(ch, pA, tag1p);
      stg_unpack(ch, s_h1[0], s_h1[1], row, ucol);
    }
    __syncthreads();
    #pragma unroll
    for (int kk = 0; kk < 8; ++kk) {   // h1 frags: used in A (Weff) and B (Whh1, pred)
      h1h_r[kk] = LDSF(s_h1[0], lcol, kk);
      h1l_r[kk] = LDSF(s_h1[1], lcol, kk);
    }
    if (t > 0) {   // Weff half (t==0: x=0, no contribution)
      #pragma unroll
      for (int kk = 0; kk < 8; ++kk) {
        ahh = MFMA16(h1h_r[kk], w0h_[kk], ahh);
        ahl = MFMA16(h1h_r[kk], w0l_[kk], ahl);
        alh = MFMA16(h1l_r[kk], w0h_[kk], alh);
      }
    }
    {
      f32x4 g = ahh + ahl + alh;
      float bb = (t == 0) ? bias0t0 : bias0;
      #pragma unroll
      for (int r = 0; r < 4; ++r) gA[wid][lrow * 4 + r][lcol] = g[r] + bb;
    }
    __syncthreads();
    {
      float gi = gA[0][urow][uu], gf = gA[1][urow][uu];
      float gg = gA[2][urow][uu], go = gA[3][urow][uu];
      float c = sigf(gf) * c0reg + sigf(gi) * tanhsafe(gg);
      c0reg = c;
      float h = sigf(go) * tanhsafe(c);
      st_htag(s0base + (size_t)wp * 65536, h, tag0);
    }

    // ================= phase B : layer1 (+ pred(t-1)) =================
    const unsigned* pB = g0base + (size_t)wp * 65536;
    stg_issue(ch, pB);   // h0(t)
    // overlap: Whh1 half (h1 regs) + pred(t-1)
    f32x4 bhh = {0.f,0.f,0.f,0.f}, bhl = {0.f,0.f,0.f,0.f}, blh = {0.f,0.f,0.f,0.f};
    #pragma unroll
    for (int kk = 0; kk < 8; ++kk) {
      bhh = MFMA16(h1h_r[kk], w1h_[kk + 8], bhh);
      bhl = MFMA16(h1h_r[kk], w1l_[kk + 8], bhl);
      blh = MFMA16(h1l_r[kk], w1h_[kk + 8], blh);
    }
    f32x4 p0 = {0.f,0.f,0.f,0.f}, p1 = {0.f,0.f,0.f,0.f}, p2 = {0.f,0.f,0.f,0.f};
    if (t > 0 && wid < 2) {
      #pragma unroll
      for (int kk = 0; kk < 8; ++kk) {
        bf16x8 fh_ = LDSF(s_fcw[0], wid * 16 + lcol, kk);
        bf16x8 fl_ = LDSF(s_fcw[1], wid * 16 + lcol, kk);
        p0 = MFMA16(h1h_r[kk], fh_, p0);
        p1 = MFMA16(h1h_r[kk], fl_, p1);
        p2 = MFMA16(h1l_r[kk], fh_, p2);
      }
    }
    wait_vm0();
    stg_validate(ch, pB, tag0);
    if (t > 0 && wid < 2 && gc == 0) {
      // pred D[row=batch=lrow*4+j][col=fc-col=lcol] -> slot 512-t
      #pragma unroll
      for (int j = 0; j < 4; ++j)
        out[(size_t)(r0 + lrow * 4 + j) * 16384 + (size_t)(512 - t) * 32 + wid * 16 + lcol] =
            p0[j] + p1[j] + p2[j] + fcbv;
    }
    stg_unpack(ch, s_h0[wp][0], s_h0[wp][1], row, ucol);
    __syncthreads();
    {
      #pragma unroll
      for (int kk = 0; kk < 8; ++kk) {
        bf16x8 fh_ = LDSF(s_h0[wp][0], lcol, kk);
        bf16x8 fl_ = LDSF(s_h0[wp][1], lcol, kk);
        bhh = MFMA16(fh_, w1h_[kk], bhh);
        bhl = MFMA16(fh_, w1l_[kk], bhl);
        blh = MFMA16(fl_, w1h_[kk], blh);
      }
      f32x4 g = bhh + bhl + blh;
      #pragma unroll
      for (int r = 0; r < 4; ++r) gA[wid][lrow * 4 + r][lcol] = g[r] + bias1;
    }
    __syncthreads();
    {
      float gi = gA[0][urow][uu], gf = gA[1][urow][uu];
      float gg = gA[2][urow][uu], go = gA[3][urow][uu];
      float c = sigf(gf) * c1reg + sigf(gi) * tanhsafe(gg);
      c1reg = c;
      float h = sigf(go) * tanhsafe(c);
      st_htag(s1base + (size_t)wp * 65536, h, tag1);
    }
  }

  // ---- tail: pred(511) from h1(511)@par1 (tag D1(511)=1) -> slot 0
  {
    u32x4 ch[4];
    const unsigned* pT = g1base + 65536;
    stg_issue(ch, pT);
    wait_vm0();
    stg_validate(ch, pT, (unsigned)(1 + (513 % 3)));
    stg_unpack(ch, s_h1[0], s_h1[1], row, ucol);
  }
  __syncthreads();
  if (wid < 2) {
    f32x4 p0 = {0.f,0.f,0.f,0.f}, p1 = {0.f,0.f,0.f,0.f}, p2 = {0.f,0.f,0.f,0.f};
    #pragma unroll
    for (int kk = 0; kk < 8; ++kk) {
      bf16x8 ah = LDSF(s_h1[0], lcol, kk);
      bf16x8 al = LDSF(s_h1[1], lcol, kk);
      bf16x8 fh_ = LDSF(s_fcw[0], wid * 16 + lcol, kk);
      bf16x8 fl_ = LDSF(s_fcw[1], wid * 16 + lcol, kk);
      p0 = MFMA16(ah, fh_, p0);
      p1 = MFMA16(ah, fl_, p1);
      p2 = MFMA16(al, fh_, p2);
    }
    if (gc == 0) {
      #pragma unroll
      for (int j = 0; j < 4; ++j)
        out[(size_t)(r0 + lrow * 4 + j) * 16384 + wid * 16 + lcol] = p0[j] + p1[j] + p2[j] + fcbv;
    }
  }
}

// ---------------- launch ----------------
extern "C" void kernel_launch(void* const* d_in, const int* in_sizes, int n_in,
                              void* d_out, int out_size, void* d_ws, size_t ws_size,
                              hipStream_t stream) {
  (void)in_sizes; (void)n_in; (void)ws_size;
  const float* input = (const float*)d_in[0];
  const float* eWih0 = (const float*)d_in[1];
  const float* eWhh0 = (const float*)d_in[2];
  const float* eb0   = (const float*)d_in[3];
  const float* eWih1 = (const float*)d_in[4];
  const float* eWhh1 = (const float*)d_in[5];
  const float* eb1   = (const float*)d_in[6];
  const float* dWih0 = (const float*)d_in[7];
  const float* dWhh0 = (const float*)d_in[8];
  const float* db0   = (const float*)d_in[9];
  const float* dWih1 = (const float*)d_in[10];
  const float* dWhh1 = (const float*)d_in[11];
  const float* db1   = (const float*)d_in[12];
  const float* fcW   = (const float*)d_in[13];
  const float* fcb   = (const float*)d_in[14];

  char* ws = (char*)d_ws;
  unsigned* h0 = (unsigned*)(ws + OFF_H0);
  unsigned* h1 = (unsigned*)(ws + OFF_H1);
  float* cfin = (float*)(ws + OFF_CFIN);
  unsigned short* ew0h = (unsigned short*)(ws + OFF_EW0H);
  unsigned short* ew0l = (unsigned short*)(ws + OFF_EW0L);
  unsigned short* ew1h = (unsigned short*)(ws + OFF_EW1H);
  unsigned short* ew1l = (unsigned short*)(ws + OFF_EW1L);
  unsigned short* dw0h = (unsigned short*)(ws + OFF_DW0H);
  unsigned short* dw0l = (unsigned short*)(ws + OFF_DW0L);
  unsigned short* dw1h = (unsigned short*)(ws + OFF_DW1H);
  unsigned short* dw1l = (unsigned short*)(ws + OFF_DW1L);
  float* beff = (float*)(ws + OFF_BEFF);
  unsigned short* fcwh = (unsigned short*)(ws + OFF_FCWH);
  unsigned short* fcwl = (unsigned short*)(ws + OFF_FCWL);

  hipMemsetAsync(d_out, 0, (size_t)out_size * sizeof(float), stream);
  hipMemsetAsync(ws + OFF_H0, 0, 2 * 524288, stream);   // h0,h1: zero data + tag 0

  k_prep_cat<<<1024, 256, 0, stream>>>(1024, eWih0, 32,  eWhh0, 256, ew0h, ew0l);
  k_prep_cat<<<1024, 256, 0, stream>>>(1024, eWih1, 256, eWhh1, 256, ew1h, ew1l);
  k_prep_cat<<<1024, 256, 0, stream>>>(1024, dWih1, 256, dWhh1, 256, dw1h, dw1l);
  k_prep_cat<<<64, 256, 0, stream>>>(32, fcW, 256, fcW, 0, fcwh, fcwl);
  k_prep_dec0<<<1024, 256, 0, stream>>>(dWih0, dWhh0, fcW, dw0h, dw0l);
  k_prep_beff<<<4, 256, 0, stream>>>(dWih0, db0, fcb, beff);

  k_encoder<<<256, 256, 0, stream>>>(input, ew0h, ew0l, ew1h, ew1l, eb0, eb1,
                                     h0, h1, cfin);
  k_decoder<<<256, 256, 0, stream>>>(dw0h, dw0l, dw1h, dw1l, beff, db0, db1, fcb,
                                     fcwh, fcwl, h0, h1, cfin, (float*)d_out);
}